// Round 1
// baseline (353.557 us; speedup 1.0000x reference)
//
#include <hip/hip_runtime.h>

// MaxUnpooling2D: out[b, 2h+dh, 2w+dw, c] = updates[b,h,w,c] where mask encodes
// the per-batch flat index ((2h+dh)*WO + (2w+dw))*C + c; all other positions 0.
// Index structure guarantees each input cell scatters only inside its own 2x2
// window -> invert to a gather: one thread owns a (h,w,c4) cell and writes all
// 4 window positions (1 value + 3 zeros). Every output element written exactly
// once: no memset pass, no atomics, minimal traffic (384 MiB total).

constexpr int B  = 16;
constexpr int H  = 128;
constexpr int W  = 128;
constexpr int C  = 64;
constexpr int UP = 2;
constexpr int HO = H * UP;   // 256
constexpr int WO = W * UP;   // 256
constexpr int C4 = C / 4;    // 16 float4 per channel-row

__global__ __launch_bounds__(256) void unpool_expand(
    const float4* __restrict__ upd,   // [B*H*W*C4]
    const int4*   __restrict__ msk,   // [B*H*W*C4]
    float4*       __restrict__ out)   // [B*HO*WO*C4]
{
    const int t = blockIdx.x * blockDim.x + threadIdx.x;   // [0, B*H*W*C4)

    // decode: c4 fastest (4 bits), then w (7 bits), h (7 bits), b (4 bits)
    const int c4 = t & (C4 - 1);
    const int w  = (t >> 4) & (W - 1);
    const int h  = (t >> 11) & (H - 1);
    const int b  = t >> 18;

    const float4 u = upd[t];
    const int4   m = msk[t];

    const int cbase = c4 * 4;
    const long obase = (long)b * ((long)HO * WO * C4);  // batch base, float4 units

#pragma unroll
    for (int dh = 0; dh < 2; ++dh) {
#pragma unroll
        for (int dw = 0; dw < 2; ++dw) {
            const int row = 2 * h + dh;
            const int col = 2 * w + dw;
            // per-batch flat float index of component 0 at this window position
            const int flat0 = (row * WO + col) * C + cbase;
            float4 v;
            v.x = (m.x == flat0 + 0) ? u.x : 0.0f;
            v.y = (m.y == flat0 + 1) ? u.y : 0.0f;
            v.z = (m.z == flat0 + 2) ? u.z : 0.0f;
            v.w = (m.w == flat0 + 3) ? u.w : 0.0f;
            out[obase + (long)(row * WO + col) * C4 + c4] = v;
        }
    }
}

extern "C" void kernel_launch(void* const* d_in, const int* in_sizes, int n_in,
                              void* d_out, int out_size, void* d_ws, size_t ws_size,
                              hipStream_t stream) {
    const float4* upd = (const float4*)d_in[0];
    const int4*   msk = (const int4*)d_in[1];
    float4*       out = (float4*)d_out;

    const int n_threads = B * H * W * C4;          // 4,194,304
    const int block = 256;
    const int grid  = n_threads / block;           // 16,384

    unpool_expand<<<grid, block, 0, stream>>>(upd, msk, out);
}

// Round 3
// 344.451 us; speedup vs baseline: 1.0264x; 1.0264x over previous
//
#include <hip/hip_runtime.h>

// MaxUnpooling2D: out[b, 2h+dh, 2w+dw, c] = updates[b,h,w,c] where mask encodes
// the per-batch flat index ((2h+dh)*WO + (2w+dw))*C + c; all other positions 0.
// Index structure guarantees each input cell scatters only inside its own 2x2
// window -> invert to a gather: one thread owns a (h,w,c4) cell and writes all
// 4 window positions (1 value + 3 zeros). Every output element written exactly
// once: no memset pass, no atomics, minimal traffic (384 MiB total).
//
// R2: nontemporal loads/stores — inputs read once, output written once and
// never re-read; bypass L2 allocation to stream at fill-rate (~6.4 TB/s).
// R3: use clang ext_vector types (HIP_vector_type structs are rejected by
// __builtin_nontemporal_*).

constexpr int B  = 16;
constexpr int H  = 128;
constexpr int W  = 128;
constexpr int C  = 64;
constexpr int UP = 2;
constexpr int HO = H * UP;   // 256
constexpr int WO = W * UP;   // 256
constexpr int C4 = C / 4;    // 16 float4 per channel-row

typedef float f32x4 __attribute__((ext_vector_type(4)));
typedef int   i32x4 __attribute__((ext_vector_type(4)));

__global__ __launch_bounds__(256) void unpool_expand(
    const f32x4* __restrict__ upd,   // [B*H*W*C4]
    const i32x4* __restrict__ msk,   // [B*H*W*C4]
    f32x4*       __restrict__ out)   // [B*HO*WO*C4]
{
    const int t = blockIdx.x * blockDim.x + threadIdx.x;   // [0, B*H*W*C4)

    // decode: c4 fastest (4 bits), then w (7 bits), h (7 bits), b (4 bits)
    const int c4 = t & (C4 - 1);
    const int w  = (t >> 4) & (W - 1);
    const int h  = (t >> 11) & (H - 1);
    const int b  = t >> 18;

    const f32x4 u = __builtin_nontemporal_load(&upd[t]);
    const i32x4 m = __builtin_nontemporal_load(&msk[t]);

    const int cbase = c4 * 4;
    const long obase = (long)b * ((long)HO * WO * C4);  // batch base, float4 units

#pragma unroll
    for (int dh = 0; dh < 2; ++dh) {
#pragma unroll
        for (int dw = 0; dw < 2; ++dw) {
            const int row = 2 * h + dh;
            const int col = 2 * w + dw;
            // per-batch flat float index of component 0 at this window position
            const int flat0 = (row * WO + col) * C + cbase;
            f32x4 v;
            v.x = (m.x == flat0 + 0) ? u.x : 0.0f;
            v.y = (m.y == flat0 + 1) ? u.y : 0.0f;
            v.z = (m.z == flat0 + 2) ? u.z : 0.0f;
            v.w = (m.w == flat0 + 3) ? u.w : 0.0f;
            __builtin_nontemporal_store(v, &out[obase + (long)(row * WO + col) * C4 + c4]);
        }
    }
}

extern "C" void kernel_launch(void* const* d_in, const int* in_sizes, int n_in,
                              void* d_out, int out_size, void* d_ws, size_t ws_size,
                              hipStream_t stream) {
    const f32x4* upd = (const f32x4*)d_in[0];
    const i32x4* msk = (const i32x4*)d_in[1];
    f32x4*       out = (f32x4*)d_out;

    const int n_threads = B * H * W * C4;          // 4,194,304
    const int block = 256;
    const int grid  = n_threads / block;           // 16,384

    unpool_expand<<<grid, block, 0, stream>>>(upd, msk, out);
}